// Round 1
// baseline (435.881 us; speedup 1.0000x reference)
//
#include <hip/hip_runtime.h>
#include <math.h>

#define TT 512
#define BB 64
#define II 256
#define HH 512
#define BH (BB*HH)      // 32768
#define TBH ((size_t)TT*BH) // 16777216

// ---------------------------------------------------------------------------
// GEMM (NT, f32): C[M][N] = A[M][K] * W[N][K]^T + bias[N]
// BM=BN=128, BK=8, 256 threads, 8x8 micro-tile per thread.
// A rows and W rows are both K-contiguous (the natural layout here).
// ---------------------------------------------------------------------------
__global__ __launch_bounds__(256)
void gemm_nt_f32(const float* __restrict__ A, const float* __restrict__ W,
                 const float* __restrict__ bias, float* __restrict__ C,
                 int M, int N, int K)
{
    const int BM = 128, BN = 128, BK = 8;
    __shared__ float As[BK][BM];   // k-major so compute reads are ds_read_b128
    __shared__ float Bs[BK][BN];

    const int bm = blockIdx.x;
    const int bn = blockIdx.y;
    const int tid = threadIdx.x;
    const int tm = tid >> 4;       // 0..15
    const int tn = tid & 15;       // 0..15
    const int row0 = bm * BM;
    const int col0 = bn * BN;

    // staging: each thread loads one float4 of A and one of W per BK step
    const int sr  = tid & 127;     // row within tile
    const int skq = tid >> 7;      // 0..1 -> which k-quad
    const float* Aptr = A + (size_t)(row0 + sr) * K + skq * 4;
    const float* Wptr = W + (size_t)(col0 + sr) * K + skq * 4;

    float acc[8][8];
#pragma unroll
    for (int i = 0; i < 8; ++i)
#pragma unroll
        for (int j = 0; j < 8; ++j) acc[i][j] = 0.f;

    float4 a_reg = *(const float4*)(Aptr);
    float4 b_reg = *(const float4*)(Wptr);

    const int NT = K / BK;
    for (int kt = 0; kt < NT; ++kt) {
        __syncthreads();
#pragma unroll
        for (int j = 0; j < 4; ++j) As[skq * 4 + j][sr] = ((const float*)&a_reg)[j];
#pragma unroll
        for (int j = 0; j < 4; ++j) Bs[skq * 4 + j][sr] = ((const float*)&b_reg)[j];
        __syncthreads();
        if (kt + 1 < NT) {   // register double-buffer: next tile overlaps compute
            a_reg = *(const float4*)(Aptr + (size_t)(kt + 1) * BK);
            b_reg = *(const float4*)(Wptr + (size_t)(kt + 1) * BK);
        }
#pragma unroll
        for (int k = 0; k < BK; ++k) {
            float af[8], bf[8];
            *(float4*)&af[0] = *(const float4*)&As[k][tm * 8];
            *(float4*)&af[4] = *(const float4*)&As[k][tm * 8 + 4];
            *(float4*)&bf[0] = *(const float4*)&Bs[k][tn * 8];
            *(float4*)&bf[4] = *(const float4*)&Bs[k][tn * 8 + 4];
#pragma unroll
            for (int i = 0; i < 8; ++i)
#pragma unroll
                for (int j = 0; j < 8; ++j)
                    acc[i][j] = fmaf(af[i], bf[j], acc[i][j]);
        }
    }

    float bj[8];
#pragma unroll
    for (int j = 0; j < 8; ++j) bj[j] = bias[col0 + tn * 8 + j];

#pragma unroll
    for (int i = 0; i < 8; ++i) {
        const int r = row0 + tm * 8 + i;
        float* Crow = C + (size_t)r * N + col0 + tn * 8;
        float4 v0, v1;
        v0.x = acc[i][0] + bj[0]; v0.y = acc[i][1] + bj[1];
        v0.z = acc[i][2] + bj[2]; v0.w = acc[i][3] + bj[3];
        v1.x = acc[i][4] + bj[4]; v1.y = acc[i][5] + bj[5];
        v1.z = acc[i][6] + bj[6]; v1.w = acc[i][7] + bj[7];
        *(float4*)(Crow)     = v0;
        *(float4*)(Crow + 4) = v1;
    }
}

// ---------------------------------------------------------------------------
// Recurrence: one thread per (b,h) column; sequential over T.
// pre may alias go (same element read-then-overwritten by the owning thread).
// 8-deep prefetch hides HBM latency of the pre[t] stream.
// ---------------------------------------------------------------------------
__global__ __launch_bounds__(64)
void skip_indrnn_rec(const float* __restrict__ pre, const float* __restrict__ h0,
                     const float* __restrict__ w_hh, const float* __restrict__ w_uh,
                     const float* __restrict__ b_uh, int layer,
                     float* __restrict__ xo, float* __restrict__ go)
{
    const int idx = blockIdx.x * blockDim.x + threadIdx.x;  // [0, BH)
    const int h = idx & (HH - 1);

    float whh = w_hh[layer * HH + h];
    whh = fminf(fmaxf(whh, -1000.f), 1000.f);      // check_bounds clip
    const float wuh = w_uh[layer * HH + h];
    const float buh = b_uh[layer];

    float hx  = h0[layer * HH + h];
    float up  = 1.f;
    float cum = 0.f;

    float cur[8], nxt[8];
#pragma unroll
    for (int j = 0; j < 8; ++j) cur[j] = pre[(size_t)j * BH + idx];

    const int NB = TT / 8;
    for (int tb = 0; tb < NB; ++tb) {
        const bool more = (tb + 1 < NB);
        if (more) {
#pragma unroll
            for (int j = 0; j < 8; ++j)
                nxt[j] = pre[(size_t)(tb * 8 + 8 + j) * BH + idx];
        }
#pragma unroll
        for (int j = 0; j < 8; ++j) {
            const int t = tb * 8 + j;
            const float nhx   = fmaxf(fmaf(whh, hx, cur[j]), 0.f);       // relu
            const float z     = fmaf(nhx, wuh, buh);
            const float tilde = 1.f / (1.f + expf(-z));                  // sigmoid
            const float c     = cum + fminf(up, 1.f - cum);
            const float g     = rintf(c);        // round-half-to-even == jnp.round
            const float nh    = (g > 0.5f) ? nhx   : hx;   // exact: g in {0,1}
            const float nup   = (g > 0.5f) ? tilde : up;
            const float ncum  = (g > 0.5f) ? 0.f   : c;
            xo[(size_t)t * BH + idx] = nh;
            go[(size_t)t * BH + idx] = g;
            hx = nh; up = nup; cum = ncum;
        }
        if (more) {
#pragma unroll
            for (int j = 0; j < 8; ++j) cur[j] = nxt[j];
        }
    }
}

// ---------------------------------------------------------------------------
extern "C" void kernel_launch(void* const* d_in, const int* in_sizes, int n_in,
                              void* d_out, int out_size, void* d_ws, size_t ws_size,
                              hipStream_t stream) {
    const float* x    = (const float*)d_in[0];  // [T,B,I]
    const float* h0   = (const float*)d_in[1];  // [L,H]
    const float* W0   = (const float*)d_in[2];  // [H,I]
    const float* W1   = (const float*)d_in[3];  // [H,H]
    const float* b_ih = (const float*)d_in[4];  // [L,H]
    const float* w_hh = (const float*)d_in[5];  // [L,H]
    const float* w_uh = (const float*)d_in[6];  // [L,H]
    const float* b_uh = (const float*)d_in[7];  // [L]

    float* out = (float*)d_out;
    float* xo0 = out;            // x_out layer 0
    float* xo1 = out + TBH;      // x_out layer 1
    float* g0  = out + 2 * TBH;  // gates layer 0
    float* g1  = out + 3 * TBH;  // gates layer 1
    float* pre = g1;             // scratch: pre-activations (overwritten by rec1)

    const dim3 gblk(256);
    const dim3 ggrid(TT * BB / 128, HH / 128);   // (256, 4)

    // Layer 0
    gemm_nt_f32<<<ggrid, gblk, 0, stream>>>(x, W0, b_ih, pre, TT * BB, HH, II);
    skip_indrnn_rec<<<BH / 64, 64, 0, stream>>>(pre, h0, w_hh, w_uh, b_uh, 0, xo0, g0);
    // Layer 1
    gemm_nt_f32<<<ggrid, gblk, 0, stream>>>(xo0, W1, b_ih + HH, pre, TT * BB, HH, HH);
    skip_indrnn_rec<<<BH / 64, 64, 0, stream>>>(pre, h0, w_hh, w_uh, b_uh, 1, xo1, g1);
}

// Round 2
// 324.724 us; speedup vs baseline: 1.3423x; 1.3423x over previous
//
#include <hip/hip_runtime.h>
#include <math.h>

#define TT 512
#define BB 64
#define II 256
#define HH 512
#define BH (BB*HH)           // 32768
#define TBH ((size_t)TT*BH)  // 16777216
#define MM (TT*BB)           // 32768

typedef float f32x4 __attribute__((ext_vector_type(4)));
typedef short s16x8 __attribute__((ext_vector_type(8)));
typedef unsigned short u16;
typedef u16 u16x4 __attribute__((ext_vector_type(4)));

__device__ __forceinline__ u16 bf16_rne(float f) {
    uint32_t u = __float_as_uint(f);
    u = (u + 0x7FFFu + ((u >> 16) & 1u)) >> 16;
    return (u16)u;
}
__device__ __forceinline__ float bf16f(u16 h) {
    return __uint_as_float(((uint32_t)h) << 16);
}

__device__ __forceinline__ void gload16(const void* g, void* l) {
    __builtin_amdgcn_global_load_lds(
        (const __attribute__((address_space(1))) unsigned int*)g,
        (__attribute__((address_space(3))) unsigned int*)l, 16, 0, 0);
}

// ---------------------------------------------------------------------------
// Planar split f32 -> (hi bf16, lo bf16), lo = rne(x - f32(hi))
// ---------------------------------------------------------------------------
__global__ __launch_bounds__(256)
void split_f32_bf16(const float* __restrict__ in, u16* __restrict__ hi,
                    u16* __restrict__ lo, size_t n4)
{
    size_t i = (size_t)blockIdx.x * 256 + threadIdx.x;
    const size_t stride = (size_t)gridDim.x * 256;
    for (; i < n4; i += stride) {
        f32x4 v = ((const f32x4*)in)[i];
        u16x4 h4, l4;
#pragma unroll
        for (int j = 0; j < 4; ++j) {
            u16 hh = bf16_rne(v[j]);
            h4[j] = hh;
            l4[j] = bf16_rne(v[j] - bf16f(hh));
        }
        ((u16x4*)hi)[i] = h4;
        ((u16x4*)lo)[i] = l4;
    }
}

// ---------------------------------------------------------------------------
// Split-2 MFMA GEMM: C[M][N] = (Ahi+Alo)[M][K] * W[N][K]^T + bias  (f32-ish)
// 128x128 tile, BK=32 bf16, 4 waves, each wave 64x64 via 4x4 16x16x32 frags.
// A planes are pre-split bf16, staged with global_load_lds (linear LDS).
// W is f32 (L2-resident), split in-kernel during staging.
// ---------------------------------------------------------------------------
__global__ __launch_bounds__(256)
void gemm_split_mfma(const u16* __restrict__ Ahi, const u16* __restrict__ Alo,
                     const float* __restrict__ W, const float* __restrict__ bias,
                     float* __restrict__ C, int M, int N, int K)
{
    __shared__ u16 As_hi[128][32];
    __shared__ u16 As_lo[128][32];
    __shared__ u16 Bs_hi[128][32];
    __shared__ u16 Bs_lo[128][32];

    const int tid  = threadIdx.x;
    const int lane = tid & 63;
    const int wid  = tid >> 6;
    const int wr   = wid >> 1, wc = wid & 1;
    const int row0 = blockIdx.x * 128;
    const int col0 = blockIdx.y * 128;

    // A gload addressing: chunk = wid*2+i covers rows [chunk*16, chunk*16+16)
    // lane deposits 16B at LDS (chunk*1024 + lane*16) == row (lane>>2), k8 (lane&3)*8
    const int a_row = lane >> 2;
    const int a_kk  = (lane & 3) * 8;

    // B staging: 2 threads per row, each 16 k-elems
    const int b_row = tid >> 1;
    const int b_kk  = (tid & 1) * 16;

    f32x4 acc[4][4];
#pragma unroll
    for (int m = 0; m < 4; ++m)
#pragma unroll
        for (int n = 0; n < 4; ++n)
#pragma unroll
            for (int r = 0; r < 4; ++r) acc[m][n][r] = 0.f;

    const int nkt = K >> 5;
    for (int kt = 0; kt < nkt; ++kt) {
        const int k0 = kt * 32;
        __syncthreads();
        // ---- stage A (bf16 planes) via global_load_lds, width 16 ----
#pragma unroll
        for (int i = 0; i < 2; ++i) {
            const int chunk = wid * 2 + i;
            const size_t gofs = (size_t)(row0 + chunk * 16 + a_row) * K + k0 + a_kk;
            gload16(Ahi + gofs, (char*)&As_hi[0][0] + chunk * 1024);
            gload16(Alo + gofs, (char*)&As_lo[0][0] + chunk * 1024);
        }
        // ---- stage B: f32 load + split + LDS write ----
        const float* wp = W + (size_t)(col0 + b_row) * K + k0 + b_kk;
#pragma unroll
        for (int q = 0; q < 4; ++q) {
            f32x4 v = *(const f32x4*)(wp + q * 4);
            u16x4 h4, l4;
#pragma unroll
            for (int j = 0; j < 4; ++j) {
                u16 hh = bf16_rne(v[j]);
                h4[j] = hh;
                l4[j] = bf16_rne(v[j] - bf16f(hh));
            }
            *(u16x4*)&Bs_hi[b_row][b_kk + q * 4] = h4;
            *(u16x4*)&Bs_lo[b_row][b_kk + q * 4] = l4;
        }
        __syncthreads();
        // ---- fragments + MFMA (48 per wave per K-step) ----
        const int ko8 = (lane >> 4) * 8;
        const int fr  = lane & 15;
        s16x8 bh[4], bl[4];
#pragma unroll
        for (int n = 0; n < 4; ++n) {
            const int col = wc * 64 + n * 16 + fr;
            bh[n] = *(const s16x8*)&Bs_hi[col][ko8];
            bl[n] = *(const s16x8*)&Bs_lo[col][ko8];
        }
#pragma unroll
        for (int m = 0; m < 4; ++m) {
            const int row = wr * 64 + m * 16 + fr;
            s16x8 ah = *(const s16x8*)&As_hi[row][ko8];
            s16x8 al = *(const s16x8*)&As_lo[row][ko8];
#pragma unroll
            for (int n = 0; n < 4; ++n) {
                acc[m][n] = __builtin_amdgcn_mfma_f32_16x16x32_bf16(ah, bh[n], acc[m][n], 0, 0, 0);
                acc[m][n] = __builtin_amdgcn_mfma_f32_16x16x32_bf16(ah, bl[n], acc[m][n], 0, 0, 0);
                acc[m][n] = __builtin_amdgcn_mfma_f32_16x16x32_bf16(al, bh[n], acc[m][n], 0, 0, 0);
            }
        }
    }

    // ---- epilogue: bias + store (C/D map: col=lane&15, row=(lane>>4)*4+r) ----
    const int fr = lane & 15, fq = lane >> 4;
#pragma unroll
    for (int n = 0; n < 4; ++n) {
        const int gc = col0 + wc * 64 + n * 16 + fr;
        const float bj = bias[gc];
#pragma unroll
        for (int m = 0; m < 4; ++m) {
            const int gr0 = row0 + wr * 64 + m * 16 + fq * 4;
#pragma unroll
            for (int r = 0; r < 4; ++r)
                C[(size_t)(gr0 + r) * N + gc] = acc[m][n][r] + bj;
        }
    }
}

// ---------------------------------------------------------------------------
// Recurrence: one thread per (b,h); optional bf16 hi/lo split of h-output
// (feeds next layer's GEMM). pre may alias go (per-thread read-then-write).
// ---------------------------------------------------------------------------
__global__ __launch_bounds__(64)
void skip_indrnn_rec(const float* __restrict__ pre, const float* __restrict__ h0,
                     const float* __restrict__ w_hh, const float* __restrict__ w_uh,
                     const float* __restrict__ b_uh, int layer,
                     float* __restrict__ xo, float* __restrict__ go,
                     u16* __restrict__ xo_hi, u16* __restrict__ xo_lo)
{
    const int idx = blockIdx.x * 64 + threadIdx.x;
    const int h = idx & (HH - 1);

    float whh = w_hh[layer * HH + h];
    whh = fminf(fmaxf(whh, -1000.f), 1000.f);
    const float wuh = w_uh[layer * HH + h];
    const float buh = b_uh[layer];

    float hx  = h0[layer * HH + h];
    float up  = 1.f;
    float cum = 0.f;

    float cur[8], nxt[8];
#pragma unroll
    for (int j = 0; j < 8; ++j) cur[j] = pre[(size_t)j * BH + idx];

    const int NB = TT / 8;
    for (int tb = 0; tb < NB; ++tb) {
        const bool more = (tb + 1 < NB);
        if (more) {
#pragma unroll
            for (int j = 0; j < 8; ++j)
                nxt[j] = pre[(size_t)(tb * 8 + 8 + j) * BH + idx];
        }
#pragma unroll
        for (int j = 0; j < 8; ++j) {
            const int t = tb * 8 + j;
            const float nhx   = fmaxf(fmaf(whh, hx, cur[j]), 0.f);
            const float z     = fmaf(nhx, wuh, buh);
            const float tilde = 1.f / (1.f + expf(-z));
            const float c     = cum + fminf(up, 1.f - cum);
            const float g     = rintf(c);
            const float nh    = (g > 0.5f) ? nhx   : hx;
            const float nup   = (g > 0.5f) ? tilde : up;
            const float ncum  = (g > 0.5f) ? 0.f   : c;
            xo[(size_t)t * BH + idx] = nh;
            go[(size_t)t * BH + idx] = g;
            if (xo_hi) {
                u16 hh = bf16_rne(nh);
                xo_hi[(size_t)t * BH + idx] = hh;
                xo_lo[(size_t)t * BH + idx] = bf16_rne(nh - bf16f(hh));
            }
            hx = nh; up = nup; cum = ncum;
        }
        if (more) {
#pragma unroll
            for (int j = 0; j < 8; ++j) cur[j] = nxt[j];
        }
    }
}

// ---------------------------------------------------------------------------
// Region plan (d_out quadrants, each TBH f32 = 67.1 MB):
//  X0 = xo0 (final)            G0 = g0 (final; x hi/lo splits before rec0)
//  X1 = xo1 (final; xo0 hi/lo splits between rec0 and rec1)
//  G1 = g1 (final; pre0 then pre1 scratch, per-thread aliased by rec)
// ---------------------------------------------------------------------------
extern "C" void kernel_launch(void* const* d_in, const int* in_sizes, int n_in,
                              void* d_out, int out_size, void* d_ws, size_t ws_size,
                              hipStream_t stream) {
    const float* x    = (const float*)d_in[0];
    const float* h0   = (const float*)d_in[1];
    const float* W0   = (const float*)d_in[2];
    const float* W1   = (const float*)d_in[3];
    const float* b_ih = (const float*)d_in[4];
    const float* w_hh = (const float*)d_in[5];
    const float* w_uh = (const float*)d_in[6];
    const float* b_uh = (const float*)d_in[7];

    float* out = (float*)d_out;
    float* X0 = out;
    float* X1 = out + TBH;
    float* G0 = out + 2 * TBH;
    float* G1 = out + 3 * TBH;

    u16* x_hi   = (u16*)G0;                    // MM*II bf16 = 16.8 MB
    u16* x_lo   = x_hi + (size_t)MM * II;
    u16* xo0_hi = (u16*)X1;                    // TBH bf16 = 33.6 MB
    u16* xo0_lo = xo0_hi + TBH;
    float* pre  = G1;

    split_f32_bf16<<<2048, 256, 0, stream>>>(x, x_hi, x_lo, (size_t)MM * II / 4);

    const dim3 ggrid(MM / 128, HH / 128);      // (256, 4)
    gemm_split_mfma<<<ggrid, 256, 0, stream>>>(x_hi, x_lo, W0, b_ih, pre, MM, HH, II);
    skip_indrnn_rec<<<BH / 64, 64, 0, stream>>>(pre, h0, w_hh, w_uh, b_uh, 0,
                                                X0, G0, xo0_hi, xo0_lo);
    gemm_split_mfma<<<ggrid, 256, 0, stream>>>(xo0_hi, xo0_lo, W1, b_ih + HH, pre, MM, HH, HH);
    skip_indrnn_rec<<<BH / 64, 64, 0, stream>>>(pre, h0, w_hh, w_uh, b_uh, 1,
                                                X1, G1, nullptr, nullptr);
}

// Round 3
// 304.094 us; speedup vs baseline: 1.4334x; 1.0678x over previous
//
#include <hip/hip_runtime.h>
#include <math.h>

#define TT 512
#define BB 64
#define II 256
#define HH 512
#define BH (BB*HH)           // 32768
#define TBH ((size_t)TT*BH)  // 16777216
#define MM (TT*BB)           // 32768

typedef float f32x4 __attribute__((ext_vector_type(4)));
typedef short s16x8 __attribute__((ext_vector_type(8)));
typedef unsigned short u16;
typedef u16 u16x4 __attribute__((ext_vector_type(4)));

__device__ __forceinline__ u16 bf16_rne(float f) {
    uint32_t u = __float_as_uint(f);
    u = (u + 0x7FFFu + ((u >> 16) & 1u)) >> 16;
    return (u16)u;
}
__device__ __forceinline__ float bf16f(u16 h) {
    return __uint_as_float(((uint32_t)h) << 16);
}

__device__ __forceinline__ void gload16(const void* g, void* l) {
    __builtin_amdgcn_global_load_lds(
        (const __attribute__((address_space(1))) unsigned int*)g,
        (__attribute__((address_space(3))) unsigned int*)l, 16, 0, 0);
}

// ---------------------------------------------------------------------------
// Planar split f32 -> (hi bf16, lo bf16), lo = rne(x - f32(hi))
// ---------------------------------------------------------------------------
__global__ __launch_bounds__(256)
void split_f32_bf16(const float* __restrict__ in, u16* __restrict__ hi,
                    u16* __restrict__ lo, size_t n4)
{
    size_t i = (size_t)blockIdx.x * 256 + threadIdx.x;
    const size_t stride = (size_t)gridDim.x * 256;
    for (; i < n4; i += stride) {
        f32x4 v = ((const f32x4*)in)[i];
        u16x4 h4, l4;
#pragma unroll
        for (int j = 0; j < 4; ++j) {
            u16 hh = bf16_rne(v[j]);
            h4[j] = hh;
            l4[j] = bf16_rne(v[j] - bf16f(hh));
        }
        ((u16x4*)hi)[i] = h4;
        ((u16x4*)lo)[i] = l4;
    }
}

// ---------------------------------------------------------------------------
// Split-2 MFMA GEMM, all-planes path:
//   C[M][N] = (Ahi+Alo)[M][K] * (Bhi+Blo)[N][K]^T + bias
// 128x128 tile, BK=32, 4 waves (2x2), 4x4 16x16x32 frags per wave.
// All four planes staged via global_load_lds (width 16, linear LDS),
// double-buffered with prefetch-next (T3 minimum 2-phase).
// ---------------------------------------------------------------------------
__global__ __launch_bounds__(256)
void gemm_planes_mfma(const u16* __restrict__ Ahi, const u16* __restrict__ Alo,
                      const u16* __restrict__ Bhi, const u16* __restrict__ Blo,
                      const float* __restrict__ bias, float* __restrict__ C,
                      int M, int N, int K)
{
    __shared__ u16 lds[2][4][128 * 32];   // [buf][plane: Ahi,Alo,Bhi,Blo]  64 KB

    const int tid  = threadIdx.x;
    const int lane = tid & 63;
    const int wid  = tid >> 6;
    const int wr   = wid >> 1, wc = wid & 1;
    const int row0 = blockIdx.x * 128;
    const int col0 = blockIdx.y * 128;

    const int a_row = lane >> 2;        // row within 16-row chunk
    const int a_kk  = (lane & 3) * 8;   // k-element offset

    f32x4 acc[4][4];
#pragma unroll
    for (int m = 0; m < 4; ++m)
#pragma unroll
        for (int n = 0; n < 4; ++n)
#pragma unroll
            for (int r = 0; r < 4; ++r) acc[m][n][r] = 0.f;

    const int nkt = K >> 5;

    auto stage = [&](int buf, int kt) {
        const int k0 = kt * 32;
#pragma unroll
        for (int i = 0; i < 2; ++i) {
            const int chunk = wid * 2 + i;          // 0..7: rows [chunk*16, +16)
            const int r = chunk * 16 + a_row;
            const size_t ga = (size_t)(row0 + r) * K + k0 + a_kk;
            const size_t gb = (size_t)(col0 + r) * K + k0 + a_kk;
            char* base = (char*)&lds[buf][0][0] + chunk * 1024;
            gload16(Ahi + ga, base);
            gload16(Alo + ga, base + 8192);
            gload16(Bhi + gb, base + 16384);
            gload16(Blo + gb, base + 24576);
        }
    };

    stage(0, 0);
    __syncthreads();                       // drains vmcnt before first reads

    for (int kt = 0; kt < nkt; ++kt) {
        const int cur = kt & 1;
        if (kt + 1 < nkt) stage(cur ^ 1, kt + 1);   // prefetch overlaps compute

        const int ko8 = (lane >> 4) * 8;
        const int fr  = lane & 15;
        const u16* AH = &lds[cur][0][0];
        const u16* AL = &lds[cur][1][0];
        const u16* BHp = &lds[cur][2][0];
        const u16* BLp = &lds[cur][3][0];

        s16x8 bh[4], bl[4];
#pragma unroll
        for (int n = 0; n < 4; ++n) {
            const int col = wc * 64 + n * 16 + fr;
            bh[n] = *(const s16x8*)&BHp[col * 32 + ko8];
            bl[n] = *(const s16x8*)&BLp[col * 32 + ko8];
        }
#pragma unroll
        for (int m = 0; m < 4; ++m) {
            const int row = wr * 64 + m * 16 + fr;
            s16x8 ah = *(const s16x8*)&AH[row * 32 + ko8];
            s16x8 al = *(const s16x8*)&AL[row * 32 + ko8];
#pragma unroll
            for (int n = 0; n < 4; ++n) {
                acc[m][n] = __builtin_amdgcn_mfma_f32_16x16x32_bf16(ah, bh[n], acc[m][n], 0, 0, 0);
                acc[m][n] = __builtin_amdgcn_mfma_f32_16x16x32_bf16(ah, bl[n], acc[m][n], 0, 0, 0);
                acc[m][n] = __builtin_amdgcn_mfma_f32_16x16x32_bf16(al, bh[n], acc[m][n], 0, 0, 0);
            }
        }
        __syncthreads();   // prefetch landed; cur safe to overwrite next iter
    }

    const int fr = lane & 15, fq = lane >> 4;
#pragma unroll
    for (int n = 0; n < 4; ++n) {
        const int gc = col0 + wc * 64 + n * 16 + fr;
        const float bj = bias[gc];
#pragma unroll
        for (int m = 0; m < 4; ++m) {
            const int gr0 = row0 + wr * 64 + m * 16 + fq * 4;
#pragma unroll
            for (int r = 0; r < 4; ++r)
                C[(size_t)(gr0 + r) * N + gc] = acc[m][n][r] + bj;
        }
    }
}

// ---------------------------------------------------------------------------
// Fallback GEMM (round-2 proven): B split in-kernel from f32 W. Used only if
// ws_size can't hold the W planes.
// ---------------------------------------------------------------------------
__global__ __launch_bounds__(256)
void gemm_split_mfma(const u16* __restrict__ Ahi, const u16* __restrict__ Alo,
                     const float* __restrict__ W, const float* __restrict__ bias,
                     float* __restrict__ C, int M, int N, int K)
{
    __shared__ u16 As_hi[128][32];
    __shared__ u16 As_lo[128][32];
    __shared__ u16 Bs_hi[128][32];
    __shared__ u16 Bs_lo[128][32];

    const int tid  = threadIdx.x;
    const int lane = tid & 63;
    const int wid  = tid >> 6;
    const int wr   = wid >> 1, wc = wid & 1;
    const int row0 = blockIdx.x * 128;
    const int col0 = blockIdx.y * 128;
    const int a_row = lane >> 2;
    const int a_kk  = (lane & 3) * 8;
    const int b_row = tid >> 1;
    const int b_kk  = (tid & 1) * 16;

    f32x4 acc[4][4];
#pragma unroll
    for (int m = 0; m < 4; ++m)
#pragma unroll
        for (int n = 0; n < 4; ++n)
#pragma unroll
            for (int r = 0; r < 4; ++r) acc[m][n][r] = 0.f;

    const int nkt = K >> 5;
    for (int kt = 0; kt < nkt; ++kt) {
        const int k0 = kt * 32;
        __syncthreads();
#pragma unroll
        for (int i = 0; i < 2; ++i) {
            const int chunk = wid * 2 + i;
            const size_t gofs = (size_t)(row0 + chunk * 16 + a_row) * K + k0 + a_kk;
            gload16(Ahi + gofs, (char*)&As_hi[0][0] + chunk * 1024);
            gload16(Alo + gofs, (char*)&As_lo[0][0] + chunk * 1024);
        }
        const float* wp = W + (size_t)(col0 + b_row) * K + k0 + b_kk;
#pragma unroll
        for (int q = 0; q < 4; ++q) {
            f32x4 v = *(const f32x4*)(wp + q * 4);
            u16x4 h4, l4;
#pragma unroll
            for (int j = 0; j < 4; ++j) {
                u16 hh = bf16_rne(v[j]);
                h4[j] = hh;
                l4[j] = bf16_rne(v[j] - bf16f(hh));
            }
            *(u16x4*)&Bs_hi[b_row][b_kk + q * 4] = h4;
            *(u16x4*)&Bs_lo[b_row][b_kk + q * 4] = l4;
        }
        __syncthreads();
        const int ko8 = (lane >> 4) * 8;
        const int fr  = lane & 15;
        s16x8 bh[4], bl[4];
#pragma unroll
        for (int n = 0; n < 4; ++n) {
            const int col = wc * 64 + n * 16 + fr;
            bh[n] = *(const s16x8*)&Bs_hi[col][ko8];
            bl[n] = *(const s16x8*)&Bs_lo[col][ko8];
        }
#pragma unroll
        for (int m = 0; m < 4; ++m) {
            const int row = wr * 64 + m * 16 + fr;
            s16x8 ah = *(const s16x8*)&As_hi[row][ko8];
            s16x8 al = *(const s16x8*)&As_lo[row][ko8];
#pragma unroll
            for (int n = 0; n < 4; ++n) {
                acc[m][n] = __builtin_amdgcn_mfma_f32_16x16x32_bf16(ah, bh[n], acc[m][n], 0, 0, 0);
                acc[m][n] = __builtin_amdgcn_mfma_f32_16x16x32_bf16(ah, bl[n], acc[m][n], 0, 0, 0);
                acc[m][n] = __builtin_amdgcn_mfma_f32_16x16x32_bf16(al, bh[n], acc[m][n], 0, 0, 0);
            }
        }
    }

    const int fr = lane & 15, fq = lane >> 4;
#pragma unroll
    for (int n = 0; n < 4; ++n) {
        const int gc = col0 + wc * 64 + n * 16 + fr;
        const float bj = bias[gc];
#pragma unroll
        for (int m = 0; m < 4; ++m) {
            const int gr0 = row0 + wr * 64 + m * 16 + fq * 4;
#pragma unroll
            for (int r = 0; r < 4; ++r)
                C[(size_t)(gr0 + r) * N + gc] = acc[m][n][r] + bj;
        }
    }
}

// ---------------------------------------------------------------------------
// Recurrence: one thread per (b,h); optional bf16 hi/lo split of h-output.
// pre may alias go (per-thread read-then-write).
// ---------------------------------------------------------------------------
__global__ __launch_bounds__(64)
void skip_indrnn_rec(const float* __restrict__ pre, const float* __restrict__ h0,
                     const float* __restrict__ w_hh, const float* __restrict__ w_uh,
                     const float* __restrict__ b_uh, int layer,
                     float* __restrict__ xo, float* __restrict__ go,
                     u16* __restrict__ xo_hi, u16* __restrict__ xo_lo)
{
    const int idx = blockIdx.x * 64 + threadIdx.x;
    const int h = idx & (HH - 1);

    float whh = w_hh[layer * HH + h];
    whh = fminf(fmaxf(whh, -1000.f), 1000.f);
    const float wuh = w_uh[layer * HH + h];
    const float buh = b_uh[layer];

    float hx  = h0[layer * HH + h];
    float up  = 1.f;
    float cum = 0.f;

    float cur[8], nxt[8];
#pragma unroll
    for (int j = 0; j < 8; ++j) cur[j] = pre[(size_t)j * BH + idx];

    const int NB = TT / 8;
    for (int tb = 0; tb < NB; ++tb) {
        const bool more = (tb + 1 < NB);
        if (more) {
#pragma unroll
            for (int j = 0; j < 8; ++j)
                nxt[j] = pre[(size_t)(tb * 8 + 8 + j) * BH + idx];
        }
#pragma unroll
        for (int j = 0; j < 8; ++j) {
            const int t = tb * 8 + j;
            const float nhx   = fmaxf(fmaf(whh, hx, cur[j]), 0.f);
            const float z     = fmaf(nhx, wuh, buh);
            const float tilde = 1.f / (1.f + expf(-z));
            const float c     = cum + fminf(up, 1.f - cum);
            const float g     = rintf(c);
            const float nh    = (g > 0.5f) ? nhx   : hx;
            const float nup   = (g > 0.5f) ? tilde : up;
            const float ncum  = (g > 0.5f) ? 0.f   : c;
            xo[(size_t)t * BH + idx] = nh;
            go[(size_t)t * BH + idx] = g;
            if (xo_hi) {
                u16 hh = bf16_rne(nh);
                xo_hi[(size_t)t * BH + idx] = hh;
                xo_lo[(size_t)t * BH + idx] = bf16_rne(nh - bf16f(hh));
            }
            hx = nh; up = nup; cum = ncum;
        }
        if (more) {
#pragma unroll
            for (int j = 0; j < 8; ++j) cur[j] = nxt[j];
        }
    }
}

// ---------------------------------------------------------------------------
// Region plan (d_out quadrants, each TBH f32 = 67.1 MB):
//  X0 = xo0 (final)            G0 = g0 (final; x hi/lo splits before rec0)
//  X1 = xo1 (final; xo0 hi/lo splits between rec0 and rec1)
//  G1 = g1 (final; pre0 then pre1 scratch, per-thread aliased by rec)
//  d_ws: W0/W1 bf16 hi/lo planes (1.5 MB), re-split every call.
// ---------------------------------------------------------------------------
extern "C" void kernel_launch(void* const* d_in, const int* in_sizes, int n_in,
                              void* d_out, int out_size, void* d_ws, size_t ws_size,
                              hipStream_t stream) {
    const float* x    = (const float*)d_in[0];
    const float* h0   = (const float*)d_in[1];
    const float* W0   = (const float*)d_in[2];
    const float* W1   = (const float*)d_in[3];
    const float* b_ih = (const float*)d_in[4];
    const float* w_hh = (const float*)d_in[5];
    const float* w_uh = (const float*)d_in[6];
    const float* b_uh = (const float*)d_in[7];

    float* out = (float*)d_out;
    float* X0 = out;
    float* X1 = out + TBH;
    float* G0 = out + 2 * TBH;
    float* G1 = out + 3 * TBH;

    u16* x_hi   = (u16*)G0;
    u16* x_lo   = x_hi + (size_t)MM * II;
    u16* xo0_hi = (u16*)X1;
    u16* xo0_lo = xo0_hi + TBH;
    float* pre  = G1;

    const size_t w_need = ((size_t)HH * II + (size_t)HH * HH) * 2 * sizeof(u16);
    const dim3 ggrid(MM / 128, HH / 128);

    split_f32_bf16<<<2048, 256, 0, stream>>>(x, x_hi, x_lo, (size_t)MM * II / 4);

    if (ws_size >= w_need) {
        u16* w0_hi = (u16*)d_ws;
        u16* w0_lo = w0_hi + (size_t)HH * II;
        u16* w1_hi = w0_lo + (size_t)HH * II;
        u16* w1_lo = w1_hi + (size_t)HH * HH;
        split_f32_bf16<<<128, 256, 0, stream>>>(W0, w0_hi, w0_lo, (size_t)HH * II / 4);
        split_f32_bf16<<<256, 256, 0, stream>>>(W1, w1_hi, w1_lo, (size_t)HH * HH / 4);

        gemm_planes_mfma<<<ggrid, 256, 0, stream>>>(x_hi, x_lo, w0_hi, w0_lo,
                                                    b_ih, pre, MM, HH, II);
        skip_indrnn_rec<<<BH / 64, 64, 0, stream>>>(pre, h0, w_hh, w_uh, b_uh, 0,
                                                    X0, G0, xo0_hi, xo0_lo);
        gemm_planes_mfma<<<ggrid, 256, 0, stream>>>(xo0_hi, xo0_lo, w1_hi, w1_lo,
                                                    b_ih + HH, pre, MM, HH, HH);
        skip_indrnn_rec<<<BH / 64, 64, 0, stream>>>(pre, h0, w_hh, w_uh, b_uh, 1,
                                                    X1, G1, nullptr, nullptr);
    } else {
        gemm_split_mfma<<<ggrid, 256, 0, stream>>>(x_hi, x_lo, W0, b_ih, pre, MM, HH, II);
        skip_indrnn_rec<<<BH / 64, 64, 0, stream>>>(pre, h0, w_hh, w_uh, b_uh, 0,
                                                    X0, G0, xo0_hi, xo0_lo);
        gemm_split_mfma<<<ggrid, 256, 0, stream>>>(xo0_hi, xo0_lo, W1, b_ih + HH,
                                                   pre, MM, HH, HH);
        skip_indrnn_rec<<<BH / 64, 64, 0, stream>>>(pre, h0, w_hh, w_uh, b_uh, 1,
                                                    X1, G1, nullptr, nullptr);
    }
}

// Round 4
// 272.635 us; speedup vs baseline: 1.5988x; 1.1154x over previous
//
#include <hip/hip_runtime.h>
#include <math.h>

#define TT 512
#define BB 64
#define II 256
#define HH 512
#define BH (BB*HH)           // 32768
#define TBH ((size_t)TT*BH)  // 16777216
#define MM (TT*BB)           // 32768

typedef float f32x4 __attribute__((ext_vector_type(4)));
typedef short s16x8 __attribute__((ext_vector_type(8)));
typedef unsigned short u16;
typedef u16 u16x4 __attribute__((ext_vector_type(4)));

__device__ __forceinline__ u16 bf16_rne(float f) {
    uint32_t u = __float_as_uint(f);
    u = (u + 0x7FFFu + ((u >> 16) & 1u)) >> 16;
    return (u16)u;
}
__device__ __forceinline__ float bf16f(u16 h) {
    return __uint_as_float(((uint32_t)h) << 16);
}

__device__ __forceinline__ void gload16(const void* g, void* l) {
    __builtin_amdgcn_global_load_lds(
        (const __attribute__((address_space(1))) unsigned int*)g,
        (__attribute__((address_space(3))) unsigned int*)l, 16, 0, 0);
}

// ---------------------------------------------------------------------------
// Planar split f32 -> (hi bf16, lo bf16), lo = rne(x - f32(hi))
// ---------------------------------------------------------------------------
__global__ __launch_bounds__(256)
void split_f32_bf16(const float* __restrict__ in, u16* __restrict__ hi,
                    u16* __restrict__ lo, size_t n4)
{
    size_t i = (size_t)blockIdx.x * 256 + threadIdx.x;
    const size_t stride = (size_t)gridDim.x * 256;
    for (; i < n4; i += stride) {
        f32x4 v = ((const f32x4*)in)[i];
        u16x4 h4, l4;
#pragma unroll
        for (int j = 0; j < 4; ++j) {
            u16 hh = bf16_rne(v[j]);
            h4[j] = hh;
            l4[j] = bf16_rne(v[j] - bf16f(hh));
        }
        ((u16x4*)hi)[i] = h4;
        ((u16x4*)lo)[i] = l4;
    }
}

// ---------------------------------------------------------------------------
// Split-2 MFMA GEMM, m97-structure (single 32 KB buffer, 2 barriers/K-step):
//   C[M][N] = (Ahi+Alo)[M][K] * (Bhi+Blo)[N][K]^T + bias
// 128x128 tile, BK=32, 4 waves (2x2), 4x4 16x16x32 frags, 3 MFMA per pair.
// All planes staged via global_load_lds (width 16, linear LDS).
// Tile order: bn-major + XCD-clustered so the 4 blocks sharing an A-panel
// run back-to-back on one XCD (A re-reads hit that XCD's L2).
// ---------------------------------------------------------------------------
__global__ __launch_bounds__(256)
void gemm_planes_mfma(const u16* __restrict__ Ahi, const u16* __restrict__ Alo,
                      const u16* __restrict__ Bhi, const u16* __restrict__ Blo,
                      const float* __restrict__ bias, float* __restrict__ C,
                      int M, int N, int K)
{
    __shared__ u16 lds[4][128 * 32];   // planes: Ahi,Alo,Bhi,Blo — 32 KB

    const int tid  = threadIdx.x;
    const int lane = tid & 63;
    const int wid  = tid >> 6;
    const int wr   = wid >> 1, wc = wid & 1;

    // XCD-clustered bn-major tile mapping (nt % 8 == 0 here: 1024 tiles)
    const int nbn = N >> 7;
    const int nt  = (M >> 7) * nbn;
    const int per = nt >> 3;
    const int logical = (blockIdx.x & 7) * per + (blockIdx.x >> 3);
    const int bm = logical / nbn;
    const int bn = logical % nbn;
    const int row0 = bm * 128;
    const int col0 = bn * 128;

    const int a_row = lane >> 2;        // row within 16-row chunk
    const int a_kk  = (lane & 3) * 8;   // k-element offset (16B granules)

    f32x4 acc[4][4];
#pragma unroll
    for (int m = 0; m < 4; ++m)
#pragma unroll
        for (int n = 0; n < 4; ++n)
#pragma unroll
            for (int r = 0; r < 4; ++r) acc[m][n][r] = 0.f;

    const int nkt = K >> 5;
    for (int kt = 0; kt < nkt; ++kt) {
        const int k0 = kt * 32;
        __syncthreads();                 // all waves done reading previous tile
#pragma unroll
        for (int i = 0; i < 2; ++i) {
            const int chunk = wid * 2 + i;              // 0..7 -> rows [chunk*16,+16)
            const int r = chunk * 16 + a_row;
            const size_t ga = (size_t)(row0 + r) * K + k0 + a_kk;
            const size_t gb = (size_t)(col0 + r) * K + k0 + a_kk;
            char* base = (char*)&lds[0][0] + chunk * 1024;
            gload16(Ahi + ga, base);
            gload16(Alo + ga, base + 8192);
            gload16(Bhi + gb, base + 16384);
            gload16(Blo + gb, base + 24576);
        }
        __syncthreads();                 // vmcnt(0) drained -> tile ready

        const int ko8 = (lane >> 4) * 8;
        const int fr  = lane & 15;
        s16x8 bh[4], bl[4];
#pragma unroll
        for (int n = 0; n < 4; ++n) {
            const int col = wc * 64 + n * 16 + fr;
            bh[n] = *(const s16x8*)&lds[2][col * 32 + ko8];
            bl[n] = *(const s16x8*)&lds[3][col * 32 + ko8];
        }
#pragma unroll
        for (int m = 0; m < 4; ++m) {
            const int row = wr * 64 + m * 16 + fr;
            s16x8 ah = *(const s16x8*)&lds[0][row * 32 + ko8];
            s16x8 al = *(const s16x8*)&lds[1][row * 32 + ko8];
#pragma unroll
            for (int n = 0; n < 4; ++n) {
                acc[m][n] = __builtin_amdgcn_mfma_f32_16x16x32_bf16(ah, bh[n], acc[m][n], 0, 0, 0);
                acc[m][n] = __builtin_amdgcn_mfma_f32_16x16x32_bf16(ah, bl[n], acc[m][n], 0, 0, 0);
                acc[m][n] = __builtin_amdgcn_mfma_f32_16x16x32_bf16(al, bh[n], acc[m][n], 0, 0, 0);
            }
        }
    }

    const int fr = lane & 15, fq = lane >> 4;
#pragma unroll
    for (int n = 0; n < 4; ++n) {
        const int gc = col0 + wc * 64 + n * 16 + fr;
        const float bj = bias[gc];
#pragma unroll
        for (int m = 0; m < 4; ++m) {
            const int gr0 = row0 + wr * 64 + m * 16 + fq * 4;
#pragma unroll
            for (int r = 0; r < 4; ++r)
                C[(size_t)(gr0 + r) * N + gc] = acc[m][n][r] + bj;
        }
    }
}

// ---------------------------------------------------------------------------
// Fallback GEMM (B split in-kernel from f32 W) — only if d_ws too small.
// ---------------------------------------------------------------------------
__global__ __launch_bounds__(256)
void gemm_split_mfma(const u16* __restrict__ Ahi, const u16* __restrict__ Alo,
                     const float* __restrict__ W, const float* __restrict__ bias,
                     float* __restrict__ C, int M, int N, int K)
{
    __shared__ u16 As_hi[128][32];
    __shared__ u16 As_lo[128][32];
    __shared__ u16 Bs_hi[128][32];
    __shared__ u16 Bs_lo[128][32];

    const int tid  = threadIdx.x;
    const int lane = tid & 63;
    const int wid  = tid >> 6;
    const int wr   = wid >> 1, wc = wid & 1;
    const int row0 = blockIdx.x * 128;
    const int col0 = blockIdx.y * 128;
    const int a_row = lane >> 2;
    const int a_kk  = (lane & 3) * 8;
    const int b_row = tid >> 1;
    const int b_kk  = (tid & 1) * 16;

    f32x4 acc[4][4];
#pragma unroll
    for (int m = 0; m < 4; ++m)
#pragma unroll
        for (int n = 0; n < 4; ++n)
#pragma unroll
            for (int r = 0; r < 4; ++r) acc[m][n][r] = 0.f;

    const int nkt = K >> 5;
    for (int kt = 0; kt < nkt; ++kt) {
        const int k0 = kt * 32;
        __syncthreads();
#pragma unroll
        for (int i = 0; i < 2; ++i) {
            const int chunk = wid * 2 + i;
            const size_t gofs = (size_t)(row0 + chunk * 16 + a_row) * K + k0 + a_kk;
            gload16(Ahi + gofs, (char*)&As_hi[0][0] + chunk * 1024);
            gload16(Alo + gofs, (char*)&As_lo[0][0] + chunk * 1024);
        }
        const float* wp = W + (size_t)(col0 + b_row) * K + k0 + b_kk;
#pragma unroll
        for (int q = 0; q < 4; ++q) {
            f32x4 v = *(const f32x4*)(wp + q * 4);
            u16x4 h4, l4;
#pragma unroll
            for (int j = 0; j < 4; ++j) {
                u16 hh = bf16_rne(v[j]);
                h4[j] = hh;
                l4[j] = bf16_rne(v[j] - bf16f(hh));
            }
            *(u16x4*)&Bs_hi[b_row][b_kk + q * 4] = h4;
            *(u16x4*)&Bs_lo[b_row][b_kk + q * 4] = l4;
        }
        __syncthreads();
        const int ko8 = (lane >> 4) * 8;
        const int fr  = lane & 15;
        s16x8 bh[4], bl[4];
#pragma unroll
        for (int n = 0; n < 4; ++n) {
            const int col = wc * 64 + n * 16 + fr;
            bh[n] = *(const s16x8*)&Bs_hi[col][ko8];
            bl[n] = *(const s16x8*)&Bs_lo[col][ko8];
        }
#pragma unroll
        for (int m = 0; m < 4; ++m) {
            const int row = wr * 64 + m * 16 + fr;
            s16x8 ah = *(const s16x8*)&As_hi[row][ko8];
            s16x8 al = *(const s16x8*)&As_lo[row][ko8];
#pragma unroll
            for (int n = 0; n < 4; ++n) {
                acc[m][n] = __builtin_amdgcn_mfma_f32_16x16x32_bf16(ah, bh[n], acc[m][n], 0, 0, 0);
                acc[m][n] = __builtin_amdgcn_mfma_f32_16x16x32_bf16(ah, bl[n], acc[m][n], 0, 0, 0);
                acc[m][n] = __builtin_amdgcn_mfma_f32_16x16x32_bf16(al, bh[n], acc[m][n], 0, 0, 0);
            }
        }
    }

    const int fr = lane & 15, fq = lane >> 4;
#pragma unroll
    for (int n = 0; n < 4; ++n) {
        const int gc = col0 + wc * 64 + n * 16 + fr;
        const float bj = bias[gc];
#pragma unroll
        for (int m = 0; m < 4; ++m) {
            const int gr0 = row0 + wr * 64 + m * 16 + fq * 4;
#pragma unroll
            for (int r = 0; r < 4; ++r)
                C[(size_t)(gr0 + r) * N + gc] = acc[m][n][r] + bj;
        }
    }
}

// ---------------------------------------------------------------------------
// Recurrence: one thread per (b,h); 16-step blocks with distance-2 prefetch
// (covers ~900 cy HBM latency with ~1000 cy of compute). Optional bf16 hi/lo
// split of h-output. pre may alias go (per-thread read-then-write: all reads
// of element t happen in prefetch ≥1 block before any write to t).
// ---------------------------------------------------------------------------
__global__ __launch_bounds__(64)
void skip_indrnn_rec(const float* __restrict__ pre, const float* __restrict__ h0,
                     const float* __restrict__ w_hh, const float* __restrict__ w_uh,
                     const float* __restrict__ b_uh, int layer,
                     float* __restrict__ xo, float* __restrict__ go,
                     u16* __restrict__ xo_hi, u16* __restrict__ xo_lo)
{
    const int idx = blockIdx.x * 64 + threadIdx.x;
    const int h = idx & (HH - 1);

    float whh = w_hh[layer * HH + h];
    whh = fminf(fmaxf(whh, -1000.f), 1000.f);
    const float wuh = w_uh[layer * HH + h];
    const float buh = b_uh[layer];

    float hx  = h0[layer * HH + h];
    float up  = 1.f;
    float cum = 0.f;

    const int SB = 16;
    const int NB = TT / SB;              // 32
    float cur[SB], nx1[SB], nx2[SB];
#pragma unroll
    for (int j = 0; j < SB; ++j) cur[j] = pre[(size_t)j * BH + idx];
#pragma unroll
    for (int j = 0; j < SB; ++j) nx1[j] = pre[(size_t)(SB + j) * BH + idx];

    for (int tb = 0; tb < NB; ++tb) {
        if (tb + 2 < NB) {
#pragma unroll
            for (int j = 0; j < SB; ++j)
                nx2[j] = pre[(size_t)((tb + 2) * SB + j) * BH + idx];
        }
#pragma unroll
        for (int j = 0; j < SB; ++j) {
            const int t = tb * SB + j;
            const float nhx   = fmaxf(fmaf(whh, hx, cur[j]), 0.f);
            const float z     = fmaf(nhx, wuh, buh);
            const float tilde = 1.f / (1.f + expf(-z));
            const float c     = cum + fminf(up, 1.f - cum);
            const float g     = rintf(c);
            const float nh    = (g > 0.5f) ? nhx   : hx;
            const float nup   = (g > 0.5f) ? tilde : up;
            const float ncum  = (g > 0.5f) ? 0.f   : c;
            xo[(size_t)t * BH + idx] = nh;
            go[(size_t)t * BH + idx] = g;
            if (xo_hi) {
                u16 hh = bf16_rne(nh);
                xo_hi[(size_t)t * BH + idx] = hh;
                xo_lo[(size_t)t * BH + idx] = bf16_rne(nh - bf16f(hh));
            }
            hx = nh; up = nup; cum = ncum;
        }
#pragma unroll
        for (int j = 0; j < SB; ++j) { cur[j] = nx1[j]; nx1[j] = nx2[j]; }
    }
}

// ---------------------------------------------------------------------------
// Region plan (d_out quadrants, each TBH f32 = 67.1 MB):
//  X0 = xo0 (final)            G0 = g0 (final; x hi/lo splits before rec0)
//  X1 = xo1 (final; xo0 hi/lo splits between rec0 and rec1)
//  G1 = g1 (final; pre0 then pre1 scratch, per-thread aliased by rec)
//  d_ws: W0/W1 bf16 hi/lo planes (1.5 MB), re-split every call.
// ---------------------------------------------------------------------------
extern "C" void kernel_launch(void* const* d_in, const int* in_sizes, int n_in,
                              void* d_out, int out_size, void* d_ws, size_t ws_size,
                              hipStream_t stream) {
    const float* x    = (const float*)d_in[0];
    const float* h0   = (const float*)d_in[1];
    const float* W0   = (const float*)d_in[2];
    const float* W1   = (const float*)d_in[3];
    const float* b_ih = (const float*)d_in[4];
    const float* w_hh = (const float*)d_in[5];
    const float* w_uh = (const float*)d_in[6];
    const float* b_uh = (const float*)d_in[7];

    float* out = (float*)d_out;
    float* X0 = out;
    float* X1 = out + TBH;
    float* G0 = out + 2 * TBH;
    float* G1 = out + 3 * TBH;

    u16* x_hi   = (u16*)G0;
    u16* x_lo   = x_hi + (size_t)MM * II;
    u16* xo0_hi = (u16*)X1;
    u16* xo0_lo = xo0_hi + TBH;
    float* pre  = G1;

    const size_t w_need = ((size_t)HH * II + (size_t)HH * HH) * 2 * sizeof(u16);

    split_f32_bf16<<<2048, 256, 0, stream>>>(x, x_hi, x_lo, (size_t)MM * II / 4);

    if (ws_size >= w_need) {
        u16* w0_hi = (u16*)d_ws;
        u16* w0_lo = w0_hi + (size_t)HH * II;
        u16* w1_hi = w0_lo + (size_t)HH * II;
        u16* w1_lo = w1_hi + (size_t)HH * HH;
        split_f32_bf16<<<128, 256, 0, stream>>>(W0, w0_hi, w0_lo, (size_t)HH * II / 4);
        split_f32_bf16<<<256, 256, 0, stream>>>(W1, w1_hi, w1_lo, (size_t)HH * HH / 4);

        gemm_planes_mfma<<<MM / 128 * (HH / 128), 256, 0, stream>>>(
            x_hi, x_lo, w0_hi, w0_lo, b_ih, pre, MM, HH, II);
        skip_indrnn_rec<<<BH / 64, 64, 0, stream>>>(pre, h0, w_hh, w_uh, b_uh, 0,
                                                    X0, G0, xo0_hi, xo0_lo);
        gemm_planes_mfma<<<MM / 128 * (HH / 128), 256, 0, stream>>>(
            xo0_hi, xo0_lo, w1_hi, w1_lo, b_ih + HH, pre, MM, HH, HH);
        skip_indrnn_rec<<<BH / 64, 64, 0, stream>>>(pre, h0, w_hh, w_uh, b_uh, 1,
                                                    X1, G1, nullptr, nullptr);
    } else {
        const dim3 ggrid(MM / 128, HH / 128);
        gemm_split_mfma<<<ggrid, 256, 0, stream>>>(x_hi, x_lo, W0, b_ih, pre, MM, HH, II);
        skip_indrnn_rec<<<BH / 64, 64, 0, stream>>>(pre, h0, w_hh, w_uh, b_uh, 0,
                                                    X0, G0, xo0_hi, xo0_lo);
        gemm_split_mfma<<<ggrid, 256, 0, stream>>>(xo0_hi, xo0_lo, W1, b_ih + HH,
                                                   pre, MM, HH, HH);
        skip_indrnn_rec<<<BH / 64, 64, 0, stream>>>(pre, h0, w_hh, w_uh, b_uh, 1,
                                                    X1, G1, nullptr, nullptr);
    }
}

// Round 5
// 246.300 us; speedup vs baseline: 1.7697x; 1.1069x over previous
//
#include <hip/hip_runtime.h>
#include <math.h>

#define TT 512
#define BB 64
#define II 256
#define HH 512
#define BH (BB*HH)           // 32768
#define TBH ((size_t)TT*BH)  // 16777216
#define MM (TT*BB)           // 32768

typedef float f32x4 __attribute__((ext_vector_type(4)));
typedef short s16x8 __attribute__((ext_vector_type(8)));
typedef unsigned short u16;
typedef u16 u16x4 __attribute__((ext_vector_type(4)));
typedef u16 u16x8 __attribute__((ext_vector_type(8)));

__device__ __forceinline__ u16 bf16_rne(float f) {
    uint32_t u = __float_as_uint(f);
    u = (u + 0x7FFFu + ((u >> 16) & 1u)) >> 16;
    return (u16)u;
}
__device__ __forceinline__ float bf16f(u16 h) {
    return __uint_as_float(((uint32_t)h) << 16);
}

// ---------------------------------------------------------------------------
// Pack W[N][K] f32 -> fragment-major bf16 hi/lo:
//   P[frag i = col*K8 + k8] = { hi[8], lo[8] }  (32 B per fragment)
// Linear: read 8 f32 at i*8, write 16 u16 at i*16.
// ---------------------------------------------------------------------------
__global__ __launch_bounds__(256)
void pack_w(const float* __restrict__ W, u16* __restrict__ P, int nfrag)
{
    const int i = blockIdx.x * 256 + threadIdx.x;
    if (i >= nfrag) return;
    const float* src = W + (size_t)i * 8;
    u16x8 h8, l8;
#pragma unroll
    for (int j = 0; j < 8; ++j) {
        const float v = src[j];
        const u16 hh = bf16_rne(v);
        h8[j] = hh;
        l8[j] = bf16_rne(v - bf16f(hh));
    }
    *(u16x8*)(P + (size_t)i * 16)     = h8;
    *(u16x8*)(P + (size_t)i * 16 + 8) = l8;
}

// ---------------------------------------------------------------------------
// Split-2 MFMA GEMM:
//   C[M][N] = A_f32[M][K] * (Whi+Wlo)[N][K]^T + bias
// A: f32, split hi/lo bf16 during LDS staging (padded [128][40] u16 planes:
//    ds_read_b128 2-way conflict = free; ds_write ~4-way on 8 ops).
// B: fragment-major packed planes, global->register with 1-step prefetch
//    (L2-resident; no B LDS at all).
// 128x128 tile, BK=32, 4 waves (2x2), 4x4 16x16x32 frags, 3 MFMA per pair
// (hi*hi + hi*lo + lo*hi; lo*lo dropped: ~2^-16 rel).
// Tile order: bn-major + XCD-clustered (4 blocks sharing an A panel run
// back-to-back on one XCD -> A re-reads hit that XCD's L2).
// ---------------------------------------------------------------------------
__global__ __launch_bounds__(256)
void gemm_f32a_packb(const float* __restrict__ A, const u16* __restrict__ Bp,
                     const float* __restrict__ bias, float* __restrict__ C,
                     int M, int N, int K)
{
    const int K8 = K >> 3;
    __shared__ u16 As[2][128][40];   // [plane hi/lo][row][k padded] = 20.5 KB

    const int tid  = threadIdx.x;
    const int lane = tid & 63;
    const int wid  = tid >> 6;
    const int wr   = wid >> 1, wc = wid & 1;

    // XCD-clustered bn-major tile mapping (nt = 1024, divisible by 8)
    const int nbn = N >> 7;
    const int nt  = (M >> 7) * nbn;
    const int per = nt >> 3;
    const int logical = (blockIdx.x & 7) * per + (blockIdx.x >> 3);
    const int bm = logical / nbn;
    const int bn = logical % nbn;
    const int row0 = bm * 128;
    const int col0 = bn * 128;

    // A staging: 2 threads per row, 16 f32 each (4x float4)
    const int s_row = tid >> 1;
    const int s_kh  = (tid & 1) * 16;
    const float* Ap = A + (size_t)(row0 + s_row) * K + s_kh;

    const int fr  = lane & 15;
    const int q   = lane >> 4;        // 0..3
    const int ko8 = q * 8;

    f32x4 acc[4][4];
#pragma unroll
    for (int m = 0; m < 4; ++m)
#pragma unroll
        for (int n = 0; n < 4; ++n)
#pragma unroll
            for (int r = 0; r < 4; ++r) acc[m][n][r] = 0.f;

    // B fragment base pointers per n (col fixed for whole kernel)
    const u16* bbase[4];
#pragma unroll
    for (int n = 0; n < 4; ++n) {
        const int col = col0 + wc * 64 + n * 16 + fr;
        bbase[n] = Bp + ((size_t)col * K8 + q) * 16;
    }

    // prologue: A regs + B frags for kt=0
    f32x4 a_ld[4];
#pragma unroll
    for (int qq = 0; qq < 4; ++qq) a_ld[qq] = *(const f32x4*)(Ap + qq * 4);

    s16x8 bh[4], bl[4], bnh[4], bnl[4];
#pragma unroll
    for (int n = 0; n < 4; ++n) {
        bh[n] = *(const s16x8*)(bbase[n]);
        bl[n] = *(const s16x8*)(bbase[n] + 8);
    }

    const int nkt = K >> 5;
    for (int kt = 0; kt < nkt; ++kt) {
        __syncthreads();               // all waves done reading LDS (prev iter)
        // ---- split + stage A ----
#pragma unroll
        for (int qq = 0; qq < 4; ++qq) {
            u16x4 h4, l4;
#pragma unroll
            for (int j = 0; j < 4; ++j) {
                const float v = a_ld[qq][j];
                const u16 hh = bf16_rne(v);
                h4[j] = hh;
                l4[j] = bf16_rne(v - bf16f(hh));
            }
            *(u16x4*)&As[0][s_row][s_kh + qq * 4] = h4;
            *(u16x4*)&As[1][s_row][s_kh + qq * 4] = l4;
        }
        __syncthreads();               // tile ready

        // ---- prefetch next K-step (overlaps MFMA below) ----
        if (kt + 1 < nkt) {
            const float* apn = Ap + (size_t)(kt + 1) * 32;
#pragma unroll
            for (int qq = 0; qq < 4; ++qq) a_ld[qq] = *(const f32x4*)(apn + qq * 4);
#pragma unroll
            for (int n = 0; n < 4; ++n) {
                const u16* f = bbase[n] + (size_t)(kt + 1) * 64;  // 4 frags * 16 u16
                bnh[n] = *(const s16x8*)(f);
                bnl[n] = *(const s16x8*)(f + 8);
            }
        }

        // ---- compute ----
#pragma unroll
        for (int m = 0; m < 4; ++m) {
            const int row = wr * 64 + m * 16 + fr;
            s16x8 ah = *(const s16x8*)&As[0][row][ko8];
            s16x8 al = *(const s16x8*)&As[1][row][ko8];
#pragma unroll
            for (int n = 0; n < 4; ++n) {
                acc[m][n] = __builtin_amdgcn_mfma_f32_16x16x32_bf16(ah, bh[n], acc[m][n], 0, 0, 0);
                acc[m][n] = __builtin_amdgcn_mfma_f32_16x16x32_bf16(ah, bl[n], acc[m][n], 0, 0, 0);
                acc[m][n] = __builtin_amdgcn_mfma_f32_16x16x32_bf16(al, bh[n], acc[m][n], 0, 0, 0);
            }
        }
#pragma unroll
        for (int n = 0; n < 4; ++n) { bh[n] = bnh[n]; bl[n] = bnl[n]; }
    }

    // ---- epilogue (C/D map: col=lane&15, row=(lane>>4)*4+r) ----
#pragma unroll
    for (int n = 0; n < 4; ++n) {
        const int gc = col0 + wc * 64 + n * 16 + fr;
        const float bj = bias[gc];
#pragma unroll
        for (int m = 0; m < 4; ++m) {
            const int gr0 = row0 + wr * 64 + m * 16 + q * 4;
#pragma unroll
            for (int r = 0; r < 4; ++r)
                C[(size_t)(gr0 + r) * N + gc] = acc[m][n][r] + bj;
        }
    }
}

// ---------------------------------------------------------------------------
// Recurrence: one thread per (b,h); 16-step blocks, distance-2 prefetch
// (~32 loads in flight covers ~900 cy HBM latency). pre may alias go:
// element t is read (prefetch, iter tb-2) before any write to t (iter tb),
// same thread, program order.
// ---------------------------------------------------------------------------
__global__ __launch_bounds__(64)
void skip_indrnn_rec(const float* __restrict__ pre, const float* __restrict__ h0,
                     const float* __restrict__ w_hh, const float* __restrict__ w_uh,
                     const float* __restrict__ b_uh, int layer,
                     float* __restrict__ xo, float* __restrict__ go)
{
    const int idx = blockIdx.x * 64 + threadIdx.x;
    const int h = idx & (HH - 1);

    float whh = w_hh[layer * HH + h];
    whh = fminf(fmaxf(whh, -1000.f), 1000.f);
    const float wuh = w_uh[layer * HH + h];
    const float buh = b_uh[layer];

    float hx  = h0[layer * HH + h];
    float up  = 1.f;
    float cum = 0.f;

    const int SB = 16;
    const int NB = TT / SB;              // 32
    float cur[SB], nx1[SB], nx2[SB];
#pragma unroll
    for (int j = 0; j < SB; ++j) cur[j] = pre[(size_t)j * BH + idx];
#pragma unroll
    for (int j = 0; j < SB; ++j) nx1[j] = pre[(size_t)(SB + j) * BH + idx];

    for (int tb = 0; tb < NB; ++tb) {
        if (tb + 2 < NB) {
#pragma unroll
            for (int j = 0; j < SB; ++j)
                nx2[j] = pre[(size_t)((tb + 2) * SB + j) * BH + idx];
        }
#pragma unroll
        for (int j = 0; j < SB; ++j) {
            const int t = tb * SB + j;
            const float nhx   = fmaxf(fmaf(whh, hx, cur[j]), 0.f);
            const float z     = fmaf(nhx, wuh, buh);
            const float tilde = 1.f / (1.f + __expf(-z));
            const float c     = cum + fminf(up, 1.f - cum);
            const float g     = rintf(c);
            const float nh    = (g > 0.5f) ? nhx   : hx;
            const float nup   = (g > 0.5f) ? tilde : up;
            const float ncum  = (g > 0.5f) ? 0.f   : c;
            xo[(size_t)t * BH + idx] = nh;
            go[(size_t)t * BH + idx] = g;
            hx = nh; up = nup; cum = ncum;
        }
#pragma unroll
        for (int j = 0; j < SB; ++j) { cur[j] = nx1[j]; nx1[j] = nx2[j]; }
    }
}

// ---------------------------------------------------------------------------
// Region plan (d_out quadrants, each TBH f32 = 67.1 MB):
//  X0 = xo0 (rec0)    G0 = g0 (rec0)
//  X1 = xo1 (rec1; holds packed W0/W1 fragments [1.6 MB] until GEMM1 done)
//  G1 = g1 (rec1; holds pre0 then pre1 scratch, per-thread aliased by rec)
// No d_ws dependency.
// ---------------------------------------------------------------------------
extern "C" void kernel_launch(void* const* d_in, const int* in_sizes, int n_in,
                              void* d_out, int out_size, void* d_ws, size_t ws_size,
                              hipStream_t stream) {
    const float* x    = (const float*)d_in[0];
    const float* h0   = (const float*)d_in[1];
    const float* W0   = (const float*)d_in[2];
    const float* W1   = (const float*)d_in[3];
    const float* b_ih = (const float*)d_in[4];
    const float* w_hh = (const float*)d_in[5];
    const float* w_uh = (const float*)d_in[6];
    const float* b_uh = (const float*)d_in[7];

    float* out = (float*)d_out;
    float* X0 = out;
    float* X1 = out + TBH;
    float* G0 = out + 2 * TBH;
    float* G1 = out + 3 * TBH;

    const int nf0 = HH * II / 8;          // 16384 fragments
    const int nf1 = HH * HH / 8;          // 32768 fragments
    u16* P0 = (u16*)X1;                   // packed W0 (dead region until rec1)
    u16* P1 = P0 + (size_t)nf0 * 16;      // packed W1
    float* pre = G1;

    pack_w<<<(nf0 + 255) / 256, 256, 0, stream>>>(W0, P0, nf0);
    pack_w<<<(nf1 + 255) / 256, 256, 0, stream>>>(W1, P1, nf1);

    gemm_f32a_packb<<<1024, 256, 0, stream>>>(x,  P0, b_ih,      pre, MM, HH, II);
    skip_indrnn_rec<<<BH / 64, 64, 0, stream>>>(pre, h0, w_hh, w_uh, b_uh, 0, X0, G0);
    gemm_f32a_packb<<<1024, 256, 0, stream>>>(X0, P1, b_ih + HH, pre, MM, HH, HH);
    skip_indrnn_rec<<<BH / 64, 64, 0, stream>>>(pre, h0, w_hh, w_uh, b_uh, 1, X1, G1);
}

// Round 6
// 240.179 us; speedup vs baseline: 1.8148x; 1.0255x over previous
//
#include <hip/hip_runtime.h>
#include <hip/hip_bf16.h>
#include <math.h>

#define TT 512
#define BB 64
#define II 256
#define HH 512
#define BH (BB*HH)           // 32768
#define TBH ((size_t)TT*BH)  // 16777216
#define MM (TT*BB)           // 32768

typedef float f32x4 __attribute__((ext_vector_type(4)));
typedef short s16x8 __attribute__((ext_vector_type(8)));
typedef unsigned short u16;
typedef u16 u16x4 __attribute__((ext_vector_type(4)));
typedef u16 u16x8 __attribute__((ext_vector_type(8)));

__device__ __forceinline__ u16 f2bf(float v) {
    __hip_bfloat16 h = __float2bfloat16(v);   // native cvt (packs to v_cvt_pk_bf16_f32)
    u16 r; __builtin_memcpy(&r, &h, 2); return r;
}
__device__ __forceinline__ float bf16f(u16 h) {
    return __uint_as_float(((uint32_t)h) << 16);
}

// ---------------------------------------------------------------------------
// Pack W0,W1 [N][K] f32 -> fragment-major bf16 hi/lo (one kernel):
//   P[frag i = col*K8 + k8] = { hi[8], lo[8] }  (32 B per fragment)
// ---------------------------------------------------------------------------
__global__ __launch_bounds__(256)
void pack_w2(const float* __restrict__ W0, const float* __restrict__ W1,
             u16* __restrict__ P0, u16* __restrict__ P1, int nf0, int nf1)
{
    const int i = blockIdx.x * 256 + threadIdx.x;
    const float* src; u16* dst;
    if (i < nf0) { src = W0 + (size_t)i * 8;         dst = P0 + (size_t)i * 16; }
    else         { const int j = i - nf0; if (j >= nf1) return;
                   src = W1 + (size_t)j * 8;         dst = P1 + (size_t)j * 16; }
    u16x8 h8, l8;
#pragma unroll
    for (int j = 0; j < 8; ++j) {
        const float v = src[j];
        const u16 hh = f2bf(v);
        h8[j] = hh;
        l8[j] = f2bf(v - bf16f(hh));
    }
    *(u16x8*)(dst)     = h8;
    *(u16x8*)(dst + 8) = l8;
}

// ---------------------------------------------------------------------------
// Split-2 MFMA GEMM:
//   C[M][N] = A_f32[M][K] * (Whi+Wlo)[N][K]^T + bias
// A: f32, split hi/lo bf16 during LDS staging via native cvt (padded
//    [128][40] u16 planes: ds_read_b128 ~2-way conflict = free).
// B: fragment-major packed planes, global->register per K-step (L2-resident,
//    no LDS, no double-buffer regs; wave overlap at 3 waves/SIMD hides L2).
// 128x128 tile, BK=32, 4 waves (2x2), 4x4 16x16x32 frags, 3 MFMA per pair
// (hi*hi + hi*lo + lo*hi; lo*lo dropped: ~2^-16 rel).
// Tile order: bn-major + XCD-clustered (4 blocks sharing an A panel run
// back-to-back on one XCD -> A re-reads hit that XCD's L2).
// ---------------------------------------------------------------------------
__global__ __launch_bounds__(256, 3)
void gemm_f32a_packb(const float* __restrict__ A, const u16* __restrict__ Bp,
                     const float* __restrict__ bias, float* __restrict__ C,
                     int M, int N, int K)
{
    const int K8 = K >> 3;
    __shared__ u16 As[2][128][40];   // [plane hi/lo][row][k padded] = 20 KB

    const int tid  = threadIdx.x;
    const int lane = tid & 63;
    const int wid  = tid >> 6;
    const int wr   = wid >> 1, wc = wid & 1;

    // XCD-clustered bn-major tile mapping (nt = 1024, divisible by 8)
    const int nbn = N >> 7;
    const int nt  = (M >> 7) * nbn;
    const int per = nt >> 3;
    const int logical = (blockIdx.x & 7) * per + (blockIdx.x >> 3);
    const int bm = logical / nbn;
    const int bn = logical % nbn;
    const int row0 = bm * 128;
    const int col0 = bn * 128;

    // A staging: 2 threads per row, 16 f32 each (4x float4)
    const int s_row = tid >> 1;
    const int s_kh  = (tid & 1) * 16;
    const float* Ap = A + (size_t)(row0 + s_row) * K + s_kh;

    const int fr  = lane & 15;
    const int q   = lane >> 4;        // 0..3
    const int ko8 = q * 8;

    f32x4 acc[4][4];
#pragma unroll
    for (int m = 0; m < 4; ++m)
#pragma unroll
        for (int n = 0; n < 4; ++n)
#pragma unroll
            for (int r = 0; r < 4; ++r) acc[m][n][r] = 0.f;

    // B fragment base pointers per n (col fixed for whole kernel)
    const u16* bbase[4];
#pragma unroll
    for (int n = 0; n < 4; ++n) {
        const int col = col0 + wc * 64 + n * 16 + fr;
        bbase[n] = Bp + ((size_t)col * K8 + q) * 16;
    }

    // prologue: A regs for kt=0
    f32x4 a_ld[4];
#pragma unroll
    for (int qq = 0; qq < 4; ++qq) a_ld[qq] = *(const f32x4*)(Ap + qq * 4);

    const int nkt = K >> 5;
    for (int kt = 0; kt < nkt; ++kt) {
        __syncthreads();               // all waves done reading LDS (prev iter)
        // ---- split + stage A (native cvt: ~3 VALU/elem) ----
#pragma unroll
        for (int qq = 0; qq < 4; ++qq) {
            u16x4 h4, l4;
#pragma unroll
            for (int j = 0; j < 4; ++j) {
                const float v = a_ld[qq][j];
                const u16 hh = f2bf(v);
                h4[j] = hh;
                l4[j] = f2bf(v - bf16f(hh));
            }
            *(u16x4*)&As[0][s_row][s_kh + qq * 4] = h4;
            *(u16x4*)&As[1][s_row][s_kh + qq * 4] = l4;
        }
        __syncthreads();               // tile ready

        // ---- B frags for this K-step (L2-resident; overlaps ds_reads) ----
        s16x8 bh[4], bl[4];
#pragma unroll
        for (int n = 0; n < 4; ++n) {
            const u16* f = bbase[n] + (size_t)kt * 64;   // 4 frags * 16 u16
            bh[n] = *(const s16x8*)(f);
            bl[n] = *(const s16x8*)(f + 8);
        }
        // ---- prefetch next A block (overlaps MFMA) ----
        if (kt + 1 < nkt) {
            const float* apn = Ap + (size_t)(kt + 1) * 32;
#pragma unroll
            for (int qq = 0; qq < 4; ++qq) a_ld[qq] = *(const f32x4*)(apn + qq * 4);
        }

        // ---- compute ----
#pragma unroll
        for (int m = 0; m < 4; ++m) {
            const int row = wr * 64 + m * 16 + fr;
            s16x8 ah = *(const s16x8*)&As[0][row][ko8];
            s16x8 al = *(const s16x8*)&As[1][row][ko8];
#pragma unroll
            for (int n = 0; n < 4; ++n) {
                acc[m][n] = __builtin_amdgcn_mfma_f32_16x16x32_bf16(ah, bh[n], acc[m][n], 0, 0, 0);
                acc[m][n] = __builtin_amdgcn_mfma_f32_16x16x32_bf16(ah, bl[n], acc[m][n], 0, 0, 0);
                acc[m][n] = __builtin_amdgcn_mfma_f32_16x16x32_bf16(al, bh[n], acc[m][n], 0, 0, 0);
            }
        }
    }

    // ---- epilogue (C/D map: col=lane&15, row=(lane>>4)*4+r) ----
#pragma unroll
    for (int n = 0; n < 4; ++n) {
        const int gc = col0 + wc * 64 + n * 16 + fr;
        const float bj = bias[gc];
#pragma unroll
        for (int m = 0; m < 4; ++m) {
            const int gr0 = row0 + wr * 64 + m * 16 + q * 4;
#pragma unroll
            for (int r = 0; r < 4; ++r)
                C[(size_t)(gr0 + r) * N + gc] = acc[m][n][r] + bj;
        }
    }
}

// ---------------------------------------------------------------------------
// Recurrence: one thread per (b,h); 16-step blocks, distance-2 prefetch
// (32 loads in flight covers ~900 cy HBM latency). pre may alias go:
// element t is read (prefetch, iter tb-2) before any write to t (iter tb),
// same thread, program order. NT stores for outputs never re-read.
// ---------------------------------------------------------------------------
template<bool NTX, bool NTG>
__global__ __launch_bounds__(64)
void skip_indrnn_rec(const float* __restrict__ pre, const float* __restrict__ h0,
                     const float* __restrict__ w_hh, const float* __restrict__ w_uh,
                     const float* __restrict__ b_uh, int layer,
                     float* __restrict__ xo, float* __restrict__ go)
{
    const int idx = blockIdx.x * 64 + threadIdx.x;
    const int h = idx & (HH - 1);

    float whh = w_hh[layer * HH + h];
    whh = fminf(fmaxf(whh, -1000.f), 1000.f);
    const float wuh = w_uh[layer * HH + h];
    const float buh = b_uh[layer];

    float hx  = h0[layer * HH + h];
    float up  = 1.f;
    float cum = 0.f;

    const int SB = 16;
    const int NB = TT / SB;              // 32
    float cur[SB], nx1[SB], nx2[SB];
#pragma unroll
    for (int j = 0; j < SB; ++j) cur[j] = pre[(size_t)j * BH + idx];
#pragma unroll
    for (int j = 0; j < SB; ++j) nx1[j] = pre[(size_t)(SB + j) * BH + idx];

    for (int tb = 0; tb < NB; ++tb) {
        if (tb + 2 < NB) {
#pragma unroll
            for (int j = 0; j < SB; ++j)
                nx2[j] = pre[(size_t)((tb + 2) * SB + j) * BH + idx];
        }
#pragma unroll
        for (int j = 0; j < SB; ++j) {
            const int t = tb * SB + j;
            const float nhx   = fmaxf(fmaf(whh, hx, cur[j]), 0.f);
            const float z     = fmaf(nhx, wuh, buh);
            const float tilde = 1.f / (1.f + __expf(-z));
            const float c     = cum + fminf(up, 1.f - cum);
            const float g     = rintf(c);
            const float nh    = (g > 0.5f) ? nhx   : hx;
            const float nup   = (g > 0.5f) ? tilde : up;
            const float ncum  = (g > 0.5f) ? 0.f   : c;
            if (NTX) __builtin_nontemporal_store(nh, &xo[(size_t)t * BH + idx]);
            else     xo[(size_t)t * BH + idx] = nh;
            if (NTG) __builtin_nontemporal_store(g, &go[(size_t)t * BH + idx]);
            else     go[(size_t)t * BH + idx] = g;
            hx = nh; up = nup; cum = ncum;
        }
#pragma unroll
        for (int j = 0; j < SB; ++j) { cur[j] = nx1[j]; nx1[j] = nx2[j]; }
    }
}

// ---------------------------------------------------------------------------
// Region plan (d_out quadrants, each TBH f32 = 67.1 MB):
//  X0 = xo0 (rec0)    G0 = g0 (rec0)
//  X1 = xo1 (rec1; holds packed W0/W1 fragments [1.6 MB] until GEMM1 done)
//  G1 = g1 (rec1; holds pre0 then pre1 scratch, per-thread aliased by rec)
// No d_ws dependency.
// ---------------------------------------------------------------------------
extern "C" void kernel_launch(void* const* d_in, const int* in_sizes, int n_in,
                              void* d_out, int out_size, void* d_ws, size_t ws_size,
                              hipStream_t stream) {
    const float* x    = (const float*)d_in[0];
    const float* h0   = (const float*)d_in[1];
    const float* W0   = (const float*)d_in[2];
    const float* W1   = (const float*)d_in[3];
    const float* b_ih = (const float*)d_in[4];
    const float* w_hh = (const float*)d_in[5];
    const float* w_uh = (const float*)d_in[6];
    const float* b_uh = (const float*)d_in[7];

    float* out = (float*)d_out;
    float* X0 = out;
    float* X1 = out + TBH;
    float* G0 = out + 2 * TBH;
    float* G1 = out + 3 * TBH;

    const int nf0 = HH * II / 8;          // 16384 fragments
    const int nf1 = HH * HH / 8;          // 32768 fragments
    u16* P0 = (u16*)X1;                   // packed W0 (dead region until rec1)
    u16* P1 = P0 + (size_t)nf0 * 16;      // packed W1
    float* pre = G1;

    pack_w2<<<(nf0 + nf1 + 255) / 256, 256, 0, stream>>>(W0, W1, P0, P1, nf0, nf1);

    gemm_f32a_packb<<<1024, 256, 0, stream>>>(x,  P0, b_ih,      pre, MM, HH, II);
    skip_indrnn_rec<false, true><<<BH / 64, 64, 0, stream>>>(pre, h0, w_hh, w_uh, b_uh, 0, X0, G0);
    gemm_f32a_packb<<<1024, 256, 0, stream>>>(X0, P1, b_ih + HH, pre, MM, HH, HH);
    skip_indrnn_rec<true, true><<<BH / 64, 64, 0, stream>>>(pre, h0, w_hh, w_uh, b_uh, 1, X1, G1);
}

// Round 7
// 190.496 us; speedup vs baseline: 2.2881x; 1.2608x over previous
//
#include <hip/hip_runtime.h>
#include <math.h>

#define TT 512
#define BB 64
#define II 256
#define HH 512
#define BH (BB*HH)           // 32768
#define TBH ((size_t)TT*BH)  // 16777216
#define MM (TT*BB)           // 32768

typedef float f32x4 __attribute__((ext_vector_type(4)));
typedef _Float16 f16x8 __attribute__((ext_vector_type(8)));
typedef unsigned short u16;
typedef u16 u16x8 __attribute__((ext_vector_type(8)));

// ---------------------------------------------------------------------------
// Pack W0,W1 [N][K] f32 -> fragment-major f16:
//   P[frag i = col*K8 + k8] = 8 f16 (16 B per fragment)
// ---------------------------------------------------------------------------
__global__ __launch_bounds__(256)
void pack_w2(const float* __restrict__ W0, const float* __restrict__ W1,
             _Float16* __restrict__ P0, _Float16* __restrict__ P1,
             int nf0, int nf1)
{
    const int i = blockIdx.x * 256 + threadIdx.x;
    const float* src; _Float16* dst;
    if (i < nf0) { src = W0 + (size_t)i * 8;  dst = P0 + (size_t)i * 8; }
    else         { const int j = i - nf0; if (j >= nf1) return;
                   src = W1 + (size_t)j * 8;  dst = P1 + (size_t)j * 8; }
    f16x8 h8;
#pragma unroll
    for (int j = 0; j < 8; ++j) h8[j] = (_Float16)src[j];
    *(f16x8*)dst = h8;
}

// ---------------------------------------------------------------------------
// f16 MFMA GEMM:  C[M][N] = A_f32[M][K] * W_f16[N][K]^T + bias
// A: f32 from HBM, cvt to f16 during LDS staging ([128][40] u16-sized padded
//    rows: 16B-aligned ds ops, ~2-way bank conflicts = free).
// B: fragment-major packed f16, global->register per K-step (L2-resident).
// 128x128 tile, BK=32, 4 waves (2x2), 4x4 16x16x32 frags, 1 MFMA per frag.
// f16 (10-bit mantissa): pre-act error ~2e-4 abs; gate saturation at large h
// makes flips live only where errors are small (see round-6 analysis).
// Tile order: bn-major + XCD-clustered.
// ---------------------------------------------------------------------------
__global__ __launch_bounds__(256, 4)
void gemm_f16(const float* __restrict__ A, const _Float16* __restrict__ Bp,
              const float* __restrict__ bias, float* __restrict__ C,
              int M, int N, int K)
{
    const int K8 = K >> 3;
    __shared__ _Float16 As[128][40];   // padded: row stride 80 B

    const int tid  = threadIdx.x;
    const int lane = tid & 63;
    const int wid  = tid >> 6;
    const int wr   = wid >> 1, wc = wid & 1;

    // XCD-clustered bn-major tile mapping (nt = 1024, divisible by 8)
    const int nbn = N >> 7;
    const int nt  = (M >> 7) * nbn;
    const int per = nt >> 3;
    const int logical = (blockIdx.x & 7) * per + (blockIdx.x >> 3);
    const int bm = logical / nbn;
    const int bn = logical % nbn;
    const int row0 = bm * 128;
    const int col0 = bn * 128;

    // A staging: 2 threads per row, 16 f32 each (4x float4)
    const int s_row = tid >> 1;
    const int s_kh  = (tid & 1) * 16;
    const float* Ap = A + (size_t)(row0 + s_row) * K + s_kh;

    const int fr  = lane & 15;
    const int q   = lane >> 4;        // 0..3
    const int ko8 = q * 8;

    f32x4 acc[4][4];
#pragma unroll
    for (int m = 0; m < 4; ++m)
#pragma unroll
        for (int n = 0; n < 4; ++n)
#pragma unroll
            for (int r = 0; r < 4; ++r) acc[m][n][r] = 0.f;

    // B fragment base pointers per n (col fixed for whole kernel)
    const _Float16* bbase[4];
#pragma unroll
    for (int n = 0; n < 4; ++n) {
        const int col = col0 + wc * 64 + n * 16 + fr;
        bbase[n] = Bp + ((size_t)col * K8 + q) * 8;
    }

    // prologue: A regs for kt=0
    f32x4 a_ld[4];
#pragma unroll
    for (int qq = 0; qq < 4; ++qq) a_ld[qq] = *(const f32x4*)(Ap + qq * 4);

    const int nkt = K >> 5;
    for (int kt = 0; kt < nkt; ++kt) {
        __syncthreads();               // all waves done reading LDS (prev iter)
        // ---- cvt + stage A (two 16B ds_writes) ----
#pragma unroll
        for (int half = 0; half < 2; ++half) {
            f16x8 h8;
#pragma unroll
            for (int j = 0; j < 8; ++j)
                h8[j] = (_Float16)a_ld[half * 2 + (j >> 2)][j & 3];
            *(f16x8*)&As[s_row][s_kh + half * 8] = h8;
        }
        __syncthreads();               // tile ready

        // ---- B frags for this K-step (L2-resident) ----
        f16x8 bfr[4];
#pragma unroll
        for (int n = 0; n < 4; ++n)
            bfr[n] = *(const f16x8*)(bbase[n] + (size_t)kt * 32);

        // ---- prefetch next A block (overlaps MFMA) ----
        if (kt + 1 < nkt) {
            const float* apn = Ap + (size_t)(kt + 1) * 32;
#pragma unroll
            for (int qq = 0; qq < 4; ++qq) a_ld[qq] = *(const f32x4*)(apn + qq * 4);
        }

        // ---- compute: 16 MFMA ----
#pragma unroll
        for (int m = 0; m < 4; ++m) {
            const int row = wr * 64 + m * 16 + fr;
            f16x8 af = *(const f16x8*)&As[row][ko8];
#pragma unroll
            for (int n = 0; n < 4; ++n)
                acc[m][n] = __builtin_amdgcn_mfma_f32_16x16x32_f16(af, bfr[n], acc[m][n], 0, 0, 0);
        }
    }

    // ---- epilogue (C/D map: col=lane&15, row=(lane>>4)*4+r) ----
#pragma unroll
    for (int n = 0; n < 4; ++n) {
        const int gc = col0 + wc * 64 + n * 16 + fr;
        const float bj = bias[gc];
#pragma unroll
        for (int m = 0; m < 4; ++m) {
            const int gr0 = row0 + wr * 64 + m * 16 + q * 4;
#pragma unroll
            for (int r = 0; r < 4; ++r)
                C[(size_t)(gr0 + r) * N + gc] = acc[m][n][r] + bj;
        }
    }
}

// ---------------------------------------------------------------------------
// Recurrence: one thread per (b,h); 16-step blocks, distance-2 prefetch
// (32 loads in flight covers ~900 cy HBM latency). pre may alias go:
// element t is read (prefetch, iter tb-2) before any write to t (iter tb),
// same thread, program order. NT stores for outputs never re-read.
// ---------------------------------------------------------------------------
template<bool NTX, bool NTG>
__global__ __launch_bounds__(64)
void skip_indrnn_rec(const float* __restrict__ pre, const float* __restrict__ h0,
                     const float* __restrict__ w_hh, const float* __restrict__ w_uh,
                     const float* __restrict__ b_uh, int layer,
                     float* __restrict__ xo, float* __restrict__ go)
{
    const int idx = blockIdx.x * 64 + threadIdx.x;
    const int h = idx & (HH - 1);

    float whh = w_hh[layer * HH + h];
    whh = fminf(fmaxf(whh, -1000.f), 1000.f);
    const float wuh = w_uh[layer * HH + h];
    const float buh = b_uh[layer];

    float hx  = h0[layer * HH + h];
    float up  = 1.f;
    float cum = 0.f;

    const int SB = 16;
    const int NB = TT / SB;              // 32
    float cur[SB], nx1[SB], nx2[SB];
#pragma unroll
    for (int j = 0; j < SB; ++j) cur[j] = pre[(size_t)j * BH + idx];
#pragma unroll
    for (int j = 0; j < SB; ++j) nx1[j] = pre[(size_t)(SB + j) * BH + idx];

    for (int tb = 0; tb < NB; ++tb) {
        if (tb + 2 < NB) {
#pragma unroll
            for (int j = 0; j < SB; ++j)
                nx2[j] = pre[(size_t)((tb + 2) * SB + j) * BH + idx];
        }
#pragma unroll
        for (int j = 0; j < SB; ++j) {
            const int t = tb * SB + j;
            const float nhx   = fmaxf(fmaf(whh, hx, cur[j]), 0.f);
            const float z     = fmaf(nhx, wuh, buh);
            const float tilde = 1.f / (1.f + __expf(-z));
            const float c     = cum + fminf(up, 1.f - cum);
            const float g     = rintf(c);
            const float nh    = (g > 0.5f) ? nhx   : hx;
            const float nup   = (g > 0.5f) ? tilde : up;
            const float ncum  = (g > 0.5f) ? 0.f   : c;
            if (NTX) __builtin_nontemporal_store(nh, &xo[(size_t)t * BH + idx]);
            else     xo[(size_t)t * BH + idx] = nh;
            if (NTG) __builtin_nontemporal_store(g, &go[(size_t)t * BH + idx]);
            else     go[(size_t)t * BH + idx] = g;
            hx = nh; up = nup; cum = ncum;
        }
#pragma unroll
        for (int j = 0; j < SB; ++j) { cur[j] = nx1[j]; nx1[j] = nx2[j]; }
    }
}

// ---------------------------------------------------------------------------
// Region plan (d_out quadrants, each TBH f32 = 67.1 MB):
//  X0 = xo0 (rec0)    G0 = g0 (rec0)
//  X1 = xo1 (rec1; holds packed W0/W1 f16 fragments [0.75 MB] until GEMM1 done)
//  G1 = g1 (rec1; holds pre0 then pre1 scratch, per-thread aliased by rec)
// No d_ws dependency.
// ---------------------------------------------------------------------------
extern "C" void kernel_launch(void* const* d_in, const int* in_sizes, int n_in,
                              void* d_out, int out_size, void* d_ws, size_t ws_size,
                              hipStream_t stream) {
    const float* x    = (const float*)d_in[0];
    const float* h0   = (const float*)d_in[1];
    const float* W0   = (const float*)d_in[2];
    const float* W1   = (const float*)d_in[3];
    const float* b_ih = (const float*)d_in[4];
    const float* w_hh = (const float*)d_in[5];
    const float* w_uh = (const float*)d_in[6];
    const float* b_uh = (const float*)d_in[7];

    float* out = (float*)d_out;
    float* X0 = out;
    float* X1 = out + TBH;
    float* G0 = out + 2 * TBH;
    float* G1 = out + 3 * TBH;

    const int nf0 = HH * II / 8;          // 16384 fragments
    const int nf1 = HH * HH / 8;          // 32768 fragments
    _Float16* P0 = (_Float16*)X1;         // packed W0 (region dead until rec1)
    _Float16* P1 = P0 + (size_t)nf0 * 8;  // packed W1
    float* pre = G1;

    pack_w2<<<(nf0 + nf1 + 255) / 256, 256, 0, stream>>>(W0, W1, P0, P1, nf0, nf1);

    gemm_f16<<<1024, 256, 0, stream>>>(x,  P0, b_ih,      pre, MM, HH, II);
    skip_indrnn_rec<false, true><<<BH / 64, 64, 0, stream>>>(pre, h0, w_hh, w_uh, b_uh, 0, X0, G0);
    gemm_f16<<<1024, 256, 0, stream>>>(X0, P1, b_ih + HH, pre, MM, HH, HH);
    skip_indrnn_rec<true, true><<<BH / 64, 64, 0, stream>>>(pre, h0, w_hh, w_uh, b_uh, 1, X1, G1);
}